// Round 2
// baseline (226.907 us; speedup 1.0000x reference)
//
#include <hip/hip_runtime.h>

// MinVarianceWeightsLayer: for each of B SPD 64x64 fp32 matrices S,
// solve S z = 1, output w = z / sum(z) as [B, 64, 1] fp32.
//
// ROUND-10: readlane broadcast, ZERO LDS.
// r9 counters proved the kernel is DS-pipe-bound: 480 wave-uniform
// ds_read_b128 per matrix at ~12 cyc each on the per-CU-shared LDS unit
// (delivering only 16 broadcast bytes each) + 8-way-conflicted publishes
// (SQ_LDS_BANK_CONFLICT = 2.95M = 15*4*8192*6 exactly) ==> ~200k DS
// cycles/CU ~= the measured 87us dispatch. VALUBusy was 25%: the per-SIMD
// VALU pipes sat idle behind the shared DS pipe.
// Fix: the broadcast source values (el0..el3) already live in lanes'
// VGPRs. Broadcast via v_readlane_b32 -> SGPR, consume via
// v_fma_f32(nf_vgpr, u_sgpr, acc_vgpr) (1 SGPR read/VALU op is legal).
// Rank-4 update moves entirely onto the per-SIMD VALU pipe; LDS deleted.
// Gauss-Jordan retained from r9 (verified correct: symmetric trailing
// block => column value el_c(j) == pivot-row value u_c(j)); no barriers,
// no cross-wave traffic of any kind.
// __launch_bounds__(256,4): cap 128 VGPRs but stop the allocator from
// squeezing to 56 (r9 showed remat below the 64 floats of r[]).

#define NN 64

typedef float v2f __attribute__((ext_vector_type(2)));
typedef float v4f __attribute__((ext_vector_type(4)));

template <int I> struct ic { static constexpr int value = I; };

template <int Start, int End, typename F>
__device__ __forceinline__ void static_for(F&& f) {
    if constexpr (Start < End) {
        f(ic<Start>{});
        static_for<Start + 1, End>(static_cast<F&&>(f));
    }
}

__device__ __forceinline__ float rlane(float v, int lane) {
    return __int_as_float(__builtin_amdgcn_readlane(__float_as_int(v), lane));
}

__device__ __forceinline__ float frcp(float x) {
#if __has_builtin(__builtin_amdgcn_rcpf)
    return __builtin_amdgcn_rcpf(x);   // ~1 ulp; plenty vs 2e-3 abs threshold
#else
    return 1.0f / x;
#endif
}

__global__ __launch_bounds__(256, 4) void minvar_kernel(const float* __restrict__ sigma,
                                                        float* __restrict__ out,
                                                        int batch) {
    const int lane = threadIdx.x & 63;
    const int wid  = threadIdx.x >> 6;     // 4 waves/block, 1 matrix each
    const int bid  = blockIdx.x * 4 + wid;
    if (bid >= batch) return;              // no barriers anywhere -> safe

    const float* __restrict__ p = sigma + (size_t)bid * (NN * NN) + (size_t)lane * NN;

    // lane i's row as 32 float2 pairs (all indices compile-time -> VGPRs)
    v2f r[NN / 2];
    static_for<0, NN / 4>([&](auto j4c) {
        constexpr int j4 = decltype(j4c)::value;
        v4f v = reinterpret_cast<const v4f*>(p)[j4];
        r[2 * j4 + 0] = v2f{v.x, v.y};
        r[2 * j4 + 1] = v2f{v.z, v.w};
    });

    float b = 1.0f;                        // RHS: ones
    float d = 1.0f;                        // this lane's pivot (set exactly once)

    static_for<0, 16>([&](auto pc) {
        constexpr int P  = decltype(pc)::value;
        constexpr int k0 = 4 * P;
        constexpr int m0 = 2 * P;          // pair-slots m0, m0+1 are the panel

        // ---- phase 1: in-panel Jordan elimination (readlane only, local) ----
        const float el0  = r[m0].x;                    // A[i][k0] (pre-panel)
        const float piv0 = rlane(el0, k0);
        const float nf0  = (lane != k0) ? (-el0 * frcp(piv0)) : 0.0f;
        d = (lane == k0) ? el0 : d;
        b = fmaf(nf0, rlane(b, k0), b);
        const float u01 = rlane(r[m0].y,     k0);
        const float u02 = rlane(r[m0 + 1].x, k0);
        const float u03 = rlane(r[m0 + 1].y, k0);
        r[m0].y     = fmaf(nf0, u01, r[m0].y);
        r[m0 + 1].x = fmaf(nf0, u02, r[m0 + 1].x);
        r[m0 + 1].y = fmaf(nf0, u03, r[m0 + 1].y);

        const float el1  = r[m0].y;                    // A[i][k0+1] after c0
        const float piv1 = rlane(el1, k0 + 1);
        const float nf1  = (lane != k0 + 1) ? (-el1 * frcp(piv1)) : 0.0f;
        d = (lane == k0 + 1) ? el1 : d;
        b = fmaf(nf1, rlane(b, k0 + 1), b);
        const float u12 = rlane(r[m0 + 1].x, k0 + 1);
        const float u13 = rlane(r[m0 + 1].y, k0 + 1);
        r[m0 + 1].x = fmaf(nf1, u12, r[m0 + 1].x);
        r[m0 + 1].y = fmaf(nf1, u13, r[m0 + 1].y);

        const float el2  = r[m0 + 1].x;                // A[i][k0+2] after c0,c1
        const float piv2 = rlane(el2, k0 + 2);
        const float nf2  = (lane != k0 + 2) ? (-el2 * frcp(piv2)) : 0.0f;
        d = (lane == k0 + 2) ? el2 : d;
        b = fmaf(nf2, rlane(b, k0 + 2), b);
        const float u23 = rlane(r[m0 + 1].y, k0 + 2);
        r[m0 + 1].y = fmaf(nf2, u23, r[m0 + 1].y);

        const float el3  = r[m0 + 1].y;                // A[i][k0+3] after c0..c2
        const float piv3 = rlane(el3, k0 + 3);
        const float nf3  = (lane != k0 + 3) ? (-el3 * frcp(piv3)) : 0.0f;
        d = (lane == k0 + 3) ? el3 : d;
        b = fmaf(nf3, rlane(b, k0 + 3), b);

        if constexpr (P < 15) {
            // ---- phase 3: rank-4 update via readlane broadcast (no LDS) ----
            // u_c(j) == el_c at lane j (symmetric trailing block, post-panel).
            static_for<m0 + 2, NN / 2>([&](auto mc) {
                constexpr int m  = decltype(mc)::value;
                constexpr int j0 = 2 * m;
                constexpr int j1 = 2 * m + 1;
                float ax = r[m].x, ay = r[m].y;
                ax = fmaf(nf0, rlane(el0, j0), ax);
                ay = fmaf(nf0, rlane(el0, j1), ay);
                ax = fmaf(nf1, rlane(el1, j0), ax);
                ay = fmaf(nf1, rlane(el1, j1), ay);
                ax = fmaf(nf2, rlane(el2, j0), ax);
                ay = fmaf(nf2, rlane(el2, j1), ay);
                ax = fmaf(nf3, rlane(el3, j0), ax);
                ay = fmaf(nf3, rlane(el3, j1), ay);
                r[m] = v2f{ax, ay};
            });
        }
    });

    // ---- diagonal system: z = b / d (no back-substitution in Gauss-Jordan) ----
    const float z = b * frcp(d);

    // ---- normalize: w = z / sum(z) ----
    float tot = z;
    #pragma unroll
    for (int off = 32; off >= 1; off >>= 1)
        tot += __shfl_xor(tot, off, 64);

    out[(size_t)bid * NN + lane] = z * frcp(tot);
}

extern "C" void kernel_launch(void* const* d_in, const int* in_sizes, int n_in,
                              void* d_out, int out_size, void* d_ws, size_t ws_size,
                              hipStream_t stream) {
    const float* sigma = (const float*)d_in[0];
    float* out = (float*)d_out;
    const int batch  = in_sizes[0] / (NN * NN);   // 8192
    const int blocks = (batch + 3) / 4;           // 4 matrices per 256-thr block
    minvar_kernel<<<blocks, 256, 0, stream>>>(sigma, out, batch);
}

// Round 3
// 211.306 us; speedup vs baseline: 1.0738x; 1.0738x over previous
//
#include <hip/hip_runtime.h>

// MinVarianceWeightsLayer: for each of B SPD 64x64 fp32 matrices S,
// solve S z = 1, output w = z / sum(z) as [B, 64, 1] fp32.
//
// ROUND-11: dual-pipe rank-4 update (LDS-broadcast + readlane split).
// Measured: pure LDS broadcast (r9) = 87us, bound on the per-CU-shared DS
// pipe (480 uniform ds_read_b128/matrix x ~12cyc), VALU 25%. Pure readlane
// (r10) = 92us, bound on the per-SIMD VALU pipe (readlane+scalar fma burn
// ~104 cyc/slot incl. allocator state-shuffle at VGPR=40), DS idle.
// These are different hardware units -> split the trailing slot-updates:
// 5/8 of slots via {2x uniform ds_read_b128 + 4x v_pk_fma}, 3/8 via
// {8x v_readlane + 8x v_fma(sgpr)}, interleaved per-slot so each wave
// feeds both pipes concurrently. Balance point from measured rates:
// T ~ max(87*x, 92-70*x) minimized near x=0.58 -> ~50us.
// Gauss-Jordan retained (no back-sub; d captured per-lane). Symmetric
// trailing block => published column value u_c(j) == el_c at lane j, so
// both paths consume the same el0..el3 registers / published words.
// One wave per matrix, no barriers (DS ops in-order within a wave).
// __launch_bounds__(256,3): VGPR cap 168 to stop the r10 squeeze-to-40.

#define NN 64

typedef float v2f __attribute__((ext_vector_type(2)));
typedef float v4f __attribute__((ext_vector_type(4)));

template <int I> struct ic { static constexpr int value = I; };

template <int Start, int End, typename F>
__device__ __forceinline__ void static_for(F&& f) {
    if constexpr (Start < End) {
        f(ic<Start>{});
        static_for<Start + 1, End>(static_cast<F&&>(f));
    }
}

__device__ __forceinline__ float rlane(float v, int lane) {
    return __int_as_float(__builtin_amdgcn_readlane(__float_as_int(v), lane));
}

__device__ __forceinline__ float frcp(float x) {
#if __has_builtin(__builtin_amdgcn_rcpf)
    return __builtin_amdgcn_rcpf(x);   // ~1 ulp; plenty vs 2e-3 abs threshold
#else
    return 1.0f / x;
#endif
}

__device__ __forceinline__ v2f fma2(v2f a, v2f b, v2f c) {
#if __has_builtin(__builtin_elementwise_fma)
    return __builtin_elementwise_fma(a, b, c);   // -> v_pk_fma_f32
#else
    v2f r; r.x = fmaf(a.x, b.x, c.x); r.y = fmaf(a.y, b.y, c.y); return r;
#endif
}

__global__ __launch_bounds__(256, 3) void minvar_kernel(const float* __restrict__ sigma,
                                                        float* __restrict__ out,
                                                        int batch) {
    // [wave][panel parity][ m*8 + c*2 + par ] : u_c[2m+par]
    __shared__ float pb[4][2][2 * NN * 4 / 2];   // 4 waves x 2 x 256 floats = 8 KB

    const int lane = threadIdx.x & 63;
    const int wid  = threadIdx.x >> 6;     // 4 waves/block, 1 matrix each
    const int bid  = blockIdx.x * 4 + wid;
    if (bid >= batch) return;              // no barriers anywhere -> safe

    const float* __restrict__ p = sigma + (size_t)bid * (NN * NN) + (size_t)lane * NN;

    // lane i's row as 32 float2 pairs (all indices compile-time -> VGPRs)
    v2f r[NN / 2];
    static_for<0, NN / 4>([&](auto j4c) {
        constexpr int j4 = decltype(j4c)::value;
        v4f v = reinterpret_cast<const v4f*>(p)[j4];
        r[2 * j4 + 0] = v2f{v.x, v.y};
        r[2 * j4 + 1] = v2f{v.z, v.w};
    });

    float b = 1.0f;                        // RHS: ones
    float d = 1.0f;                        // this lane's pivot (set exactly once)
    const int wbase = (lane >> 1) * 8 + (lane & 1);   // scatter-write index

    static_for<0, 16>([&](auto pc) {
        constexpr int P  = decltype(pc)::value;
        constexpr int k0 = 4 * P;
        constexpr int m0 = 2 * P;          // pair-slots m0, m0+1 are the panel
        float* __restrict__ wb = &pb[wid][P & 1][0];

        // ---- phase 1: in-panel Jordan elimination (readlane only, local) ----
        const float el0  = r[m0].x;                    // A[i][k0] (pre-panel)
        if constexpr (P < 15) wb[wbase + 0] = el0;     // publish early
        const float piv0 = rlane(el0, k0);
        const float nf0  = (lane != k0) ? (-el0 * frcp(piv0)) : 0.0f;
        d = (lane == k0) ? el0 : d;
        b = fmaf(nf0, rlane(b, k0), b);
        const float u01 = rlane(r[m0].y,     k0);
        const float u02 = rlane(r[m0 + 1].x, k0);
        const float u03 = rlane(r[m0 + 1].y, k0);
        r[m0].y     = fmaf(nf0, u01, r[m0].y);
        r[m0 + 1].x = fmaf(nf0, u02, r[m0 + 1].x);
        r[m0 + 1].y = fmaf(nf0, u03, r[m0 + 1].y);

        const float el1  = r[m0].y;                    // A[i][k0+1] after c0
        if constexpr (P < 15) wb[wbase + 2] = el1;
        const float piv1 = rlane(el1, k0 + 1);
        const float nf1  = (lane != k0 + 1) ? (-el1 * frcp(piv1)) : 0.0f;
        d = (lane == k0 + 1) ? el1 : d;
        b = fmaf(nf1, rlane(b, k0 + 1), b);
        const float u12 = rlane(r[m0 + 1].x, k0 + 1);
        const float u13 = rlane(r[m0 + 1].y, k0 + 1);
        r[m0 + 1].x = fmaf(nf1, u12, r[m0 + 1].x);
        r[m0 + 1].y = fmaf(nf1, u13, r[m0 + 1].y);

        const float el2  = r[m0 + 1].x;                // A[i][k0+2] after c0,c1
        if constexpr (P < 15) wb[wbase + 4] = el2;
        const float piv2 = rlane(el2, k0 + 2);
        const float nf2  = (lane != k0 + 2) ? (-el2 * frcp(piv2)) : 0.0f;
        d = (lane == k0 + 2) ? el2 : d;
        b = fmaf(nf2, rlane(b, k0 + 2), b);
        const float u23 = rlane(r[m0 + 1].y, k0 + 2);
        r[m0 + 1].y = fmaf(nf2, u23, r[m0 + 1].y);

        const float el3  = r[m0 + 1].y;                // A[i][k0+3] after c0..c2
        if constexpr (P < 15) wb[wbase + 6] = el3;
        const float piv3 = rlane(el3, k0 + 3);
        const float nf3  = (lane != k0 + 3) ? (-el3 * frcp(piv3)) : 0.0f;
        d = (lane == k0 + 3) ? el3 : d;
        b = fmaf(nf3, rlane(b, k0 + 3), b);

        if constexpr (P < 15) {
            // ---- phase 3: rank-4 update, split across DS and VALU pipes ----
            const v2f n0 = v2f{nf0, nf0}, n1 = v2f{nf1, nf1};
            const v2f n2 = v2f{nf2, nf2}, n3 = v2f{nf3, nf3};
            static_for<m0 + 2, NN / 2>([&](auto mc) {
                constexpr int m = decltype(mc)::value;
                if constexpr (((m - m0) & 7) < 5) {
                    // LDS-broadcast path: 2 uniform ds_read_b128 + 4 pk_fma
                    const v4f lo = *reinterpret_cast<const v4f*>(wb + 8 * m);
                    const v4f hi = *reinterpret_cast<const v4f*>(wb + 8 * m + 4);
                    v2f acc = r[m];
                    acc = fma2(n0, v2f{lo.x, lo.y}, acc);
                    acc = fma2(n1, v2f{lo.z, lo.w}, acc);
                    acc = fma2(n2, v2f{hi.x, hi.y}, acc);
                    acc = fma2(n3, v2f{hi.z, hi.w}, acc);
                    r[m] = acc;
                } else {
                    // readlane path: 8 v_readlane + 8 v_fma (sgpr operand)
                    constexpr int j0 = 2 * m, j1 = 2 * m + 1;
                    float ax = r[m].x, ay = r[m].y;
                    ax = fmaf(nf0, rlane(el0, j0), ax);
                    ay = fmaf(nf0, rlane(el0, j1), ay);
                    ax = fmaf(nf1, rlane(el1, j0), ax);
                    ay = fmaf(nf1, rlane(el1, j1), ay);
                    ax = fmaf(nf2, rlane(el2, j0), ax);
                    ay = fmaf(nf2, rlane(el2, j1), ay);
                    ax = fmaf(nf3, rlane(el3, j0), ax);
                    ay = fmaf(nf3, rlane(el3, j1), ay);
                    r[m] = v2f{ax, ay};
                }
            });
        }
    });

    // ---- diagonal system: z = b / d (no back-substitution in Gauss-Jordan) ----
    const float z = b * frcp(d);

    // ---- normalize: w = z / sum(z) ----
    float tot = z;
    #pragma unroll
    for (int off = 32; off >= 1; off >>= 1)
        tot += __shfl_xor(tot, off, 64);

    out[(size_t)bid * NN + lane] = z * frcp(tot);
}

extern "C" void kernel_launch(void* const* d_in, const int* in_sizes, int n_in,
                              void* d_out, int out_size, void* d_ws, size_t ws_size,
                              hipStream_t stream) {
    const float* sigma = (const float*)d_in[0];
    float* out = (float*)d_out;
    const int batch  = in_sizes[0] / (NN * NN);   // 8192
    const int blocks = (batch + 3) / 4;           // 4 matrices per 256-thr block
    minvar_kernel<<<blocks, 256, 0, stream>>>(sigma, out, batch);
}

// Round 4
// 192.234 us; speedup vs baseline: 1.1804x; 1.0992x over previous
//
#include <hip/hip_runtime.h>

// MinVarianceWeightsLayer: for each of B SPD 64x64 fp32 matrices S,
// solve S z = 1, output w = z / sum(z) as [B, 64, 1] fp32.
//
// ROUND-12: fix the register squeeze + explicit DS/VALU software pipeline.
// r8-r11 all show VGPR_Count (40/52/56) BELOW the 64 floats of r[] alone:
// LLVM's scheduler targets 8 waves/EU by default and squeezes arch VGPRs
// by spilling r[] to AGPRs + serializing live ranges. Actual residency is
// ~4 waves/SIMD regardless (occupancy 35-48%), so the squeeze pays pure
// overhead: accvgpr shuffles in every dependency chain and zero slot ILP
// (r10: ~100 cyc effective per 16-instr slot). Fix 1: amdgpu_waves_per_eu(3,4)
// caps the occupancy TARGET at 4 -> register budget 128-170, no squeeze.
// Fix 2: r11's dual-pipe split ran DS and VALU back-to-back (dur ~= sum,
// not max: each pk_fma waits right behind its own ds_read). Restructure
// phase 3 into groups of 8 slots: issue 5 LDS-slots' ds_read_b128 into
// compile-time-indexed register arrays, run 3 readlane-slots while the DS
// data flies, then consume the prefetched slots. ~48 VALU cycles of
// independent work now cover each group's DS latency.
// Gauss-Jordan retained (no back-sub); symmetric trailing block =>
// published column value u_c(j) == el_c at lane j for both transports.
// One wave per matrix, no barriers (DS ops in-order within a wave).

#define NN 64

typedef float v2f __attribute__((ext_vector_type(2)));
typedef float v4f __attribute__((ext_vector_type(4)));

template <int I> struct ic { static constexpr int value = I; };

template <int Start, int End, typename F>
__device__ __forceinline__ void static_for(F&& f) {
    if constexpr (Start < End) {
        f(ic<Start>{});
        static_for<Start + 1, End>(static_cast<F&&>(f));
    }
}

__device__ __forceinline__ float rlane(float v, int lane) {
    return __int_as_float(__builtin_amdgcn_readlane(__float_as_int(v), lane));
}

__device__ __forceinline__ float frcp(float x) {
#if __has_builtin(__builtin_amdgcn_rcpf)
    return __builtin_amdgcn_rcpf(x);   // ~1 ulp; plenty vs 2e-3 abs threshold
#else
    return 1.0f / x;
#endif
}

__device__ __forceinline__ v2f fma2(v2f a, v2f b, v2f c) {
#if __has_builtin(__builtin_elementwise_fma)
    return __builtin_elementwise_fma(a, b, c);   // -> v_pk_fma_f32
#else
    v2f r; r.x = fmaf(a.x, b.x, c.x); r.y = fmaf(a.y, b.y, c.y); return r;
#endif
}

__global__
__attribute__((amdgpu_flat_work_group_size(256, 256), amdgpu_waves_per_eu(3, 4)))
void minvar_kernel(const float* __restrict__ sigma,
                   float* __restrict__ out,
                   int batch) {
    // [wave][panel parity][ m*8 + c*2 + par ] : u_c[2m+par]
    __shared__ float pb[4][2][2 * NN * 4 / 2];   // 4 waves x 2 x 256 floats = 8 KB

    const int lane = threadIdx.x & 63;
    const int wid  = threadIdx.x >> 6;     // 4 waves/block, 1 matrix each
    const int bid  = blockIdx.x * 4 + wid;
    if (bid >= batch) return;              // no barriers anywhere -> safe

    const float* __restrict__ p = sigma + (size_t)bid * (NN * NN) + (size_t)lane * NN;

    // lane i's row as 32 float2 pairs (all indices compile-time -> VGPRs)
    v2f r[NN / 2];
    static_for<0, NN / 4>([&](auto j4c) {
        constexpr int j4 = decltype(j4c)::value;
        v4f v = reinterpret_cast<const v4f*>(p)[j4];
        r[2 * j4 + 0] = v2f{v.x, v.y};
        r[2 * j4 + 1] = v2f{v.z, v.w};
    });

    float b = 1.0f;                        // RHS: ones
    float d = 1.0f;                        // this lane's pivot (set exactly once)
    const int wbase = (lane >> 1) * 8 + (lane & 1);   // scatter-write index

    static_for<0, 16>([&](auto pc) {
        constexpr int P  = decltype(pc)::value;
        constexpr int k0 = 4 * P;
        constexpr int m0 = 2 * P;          // pair-slots m0, m0+1 are the panel
        float* __restrict__ wb = &pb[wid][P & 1][0];

        // ---- phase 1: in-panel Jordan elimination (readlane only, local) ----
        const float el0  = r[m0].x;                    // A[i][k0] (pre-panel)
        if constexpr (P < 15) wb[wbase + 0] = el0;     // publish early
        const float piv0 = rlane(el0, k0);
        const float nf0  = (lane != k0) ? (-el0 * frcp(piv0)) : 0.0f;
        d = (lane == k0) ? el0 : d;
        b = fmaf(nf0, rlane(b, k0), b);
        const float u01 = rlane(r[m0].y,     k0);
        const float u02 = rlane(r[m0 + 1].x, k0);
        const float u03 = rlane(r[m0 + 1].y, k0);
        r[m0].y     = fmaf(nf0, u01, r[m0].y);
        r[m0 + 1].x = fmaf(nf0, u02, r[m0 + 1].x);
        r[m0 + 1].y = fmaf(nf0, u03, r[m0 + 1].y);

        const float el1  = r[m0].y;                    // A[i][k0+1] after c0
        if constexpr (P < 15) wb[wbase + 2] = el1;
        const float piv1 = rlane(el1, k0 + 1);
        const float nf1  = (lane != k0 + 1) ? (-el1 * frcp(piv1)) : 0.0f;
        d = (lane == k0 + 1) ? el1 : d;
        b = fmaf(nf1, rlane(b, k0 + 1), b);
        const float u12 = rlane(r[m0 + 1].x, k0 + 1);
        const float u13 = rlane(r[m0 + 1].y, k0 + 1);
        r[m0 + 1].x = fmaf(nf1, u12, r[m0 + 1].x);
        r[m0 + 1].y = fmaf(nf1, u13, r[m0 + 1].y);

        const float el2  = r[m0 + 1].x;                // A[i][k0+2] after c0,c1
        if constexpr (P < 15) wb[wbase + 4] = el2;
        const float piv2 = rlane(el2, k0 + 2);
        const float nf2  = (lane != k0 + 2) ? (-el2 * frcp(piv2)) : 0.0f;
        d = (lane == k0 + 2) ? el2 : d;
        b = fmaf(nf2, rlane(b, k0 + 2), b);
        const float u23 = rlane(r[m0 + 1].y, k0 + 2);
        r[m0 + 1].y = fmaf(nf2, u23, r[m0 + 1].y);

        const float el3  = r[m0 + 1].y;                // A[i][k0+3] after c0..c2
        if constexpr (P < 15) wb[wbase + 6] = el3;
        const float piv3 = rlane(el3, k0 + 3);
        const float nf3  = (lane != k0 + 3) ? (-el3 * frcp(piv3)) : 0.0f;
        d = (lane == k0 + 3) ? el3 : d;
        b = fmaf(nf3, rlane(b, k0 + 3), b);

        if constexpr (P < 15) {
            // ---- phase 3: rank-4 update, software-pipelined dual-pipe ----
            // Groups of 8 trailing slots: 5 LDS-prefetch slots + 3 readlane
            // slots. DS reads issue first, readlane slots cover the latency,
            // then the prefetched slots are consumed.
            const v2f n0 = v2f{nf0, nf0}, n1 = v2f{nf1, nf1};
            const v2f n2 = v2f{nf2, nf2}, n3 = v2f{nf3, nf3};
            static_for<0, 4>([&](auto gc) {
                constexpr int G = decltype(gc)::value;
                constexpr int s = m0 + 2 + 8 * G;
                if constexpr (s < NN / 2) {
                    constexpr int e = (s + 8 < NN / 2) ? (s + 8) : (NN / 2);
                    v4f lo[5], hi[5];
                    // pass A: issue DS reads for LDS slots (q = 0..4)
                    static_for<s, e>([&](auto mc) {
                        constexpr int m = decltype(mc)::value;
                        constexpr int q = m - s;
                        if constexpr (q < 5) {
                            lo[q] = *reinterpret_cast<const v4f*>(wb + 8 * m);
                            hi[q] = *reinterpret_cast<const v4f*>(wb + 8 * m + 4);
                        }
                    });
                    // pass B: readlane slots (q = 5..7) — independent of DS
                    static_for<s, e>([&](auto mc) {
                        constexpr int m = decltype(mc)::value;
                        constexpr int q = m - s;
                        if constexpr (q >= 5) {
                            constexpr int j0 = 2 * m, j1 = 2 * m + 1;
                            float ax = r[m].x, ay = r[m].y;
                            ax = fmaf(nf0, rlane(el0, j0), ax);
                            ay = fmaf(nf0, rlane(el0, j1), ay);
                            ax = fmaf(nf1, rlane(el1, j0), ax);
                            ay = fmaf(nf1, rlane(el1, j1), ay);
                            ax = fmaf(nf2, rlane(el2, j0), ax);
                            ay = fmaf(nf2, rlane(el2, j1), ay);
                            ax = fmaf(nf3, rlane(el3, j0), ax);
                            ay = fmaf(nf3, rlane(el3, j1), ay);
                            r[m] = v2f{ax, ay};
                        }
                    });
                    // pass C: consume prefetched LDS data
                    static_for<s, e>([&](auto mc) {
                        constexpr int m = decltype(mc)::value;
                        constexpr int q = m - s;
                        if constexpr (q < 5) {
                            v2f acc = r[m];
                            acc = fma2(n0, v2f{lo[q].x, lo[q].y}, acc);
                            acc = fma2(n1, v2f{lo[q].z, lo[q].w}, acc);
                            acc = fma2(n2, v2f{hi[q].x, hi[q].y}, acc);
                            acc = fma2(n3, v2f{hi[q].z, hi[q].w}, acc);
                            r[m] = acc;
                        }
                    });
                }
            });
        }
    });

    // ---- diagonal system: z = b / d (no back-substitution in Gauss-Jordan) ----
    const float z = b * frcp(d);

    // ---- normalize: w = z / sum(z) ----
    float tot = z;
    #pragma unroll
    for (int off = 32; off >= 1; off >>= 1)
        tot += __shfl_xor(tot, off, 64);

    out[(size_t)bid * NN + lane] = z * frcp(tot);
}

extern "C" void kernel_launch(void* const* d_in, const int* in_sizes, int n_in,
                              void* d_out, int out_size, void* d_ws, size_t ws_size,
                              hipStream_t stream) {
    const float* sigma = (const float*)d_in[0];
    float* out = (float*)d_out;
    const int batch  = in_sizes[0] / (NN * NN);   // 8192
    const int blocks = (batch + 3) / 4;           // 4 matrices per 256-thr block
    minvar_kernel<<<blocks, 256, 0, stream>>>(sigma, out, batch);
}